// Round 1
// 303.235 us; speedup vs baseline: 1.0107x; 1.0107x over previous
//
#include <hip/hip_runtime.h>
#include <math.h>

#define NROWS 131072
#define NMODS 6
#define NPREDS 30
#define RPG 4                      // rows per group (one wave iteration)
#define NGROUPS (NROWS / RPG)      // 32768
#define NBLK 2048
#define NWAVES (NBLK * 4)          // 8192 -> 4 groups per wave

// d_ws: 12 accumulator slots, 256 B apart:
// 0 ade6x, 1 ade6y, 2 fde6x, 3 fde6y, 4 ade1x, 5 ade1y, 6 fde1x, 7 fde1y,
// 8 regloss, 9 summgn, 10 numcls, 11 numreg
#define ACC_SLOT(ws, i) ((float*)((char*)(ws) + (size_t)(i) * 256))

// s_waitcnt lgkmcnt(0) ONLY (vmcnt=63, expcnt=7 untouched) — does not drain
// in-flight global loads.
#define LGKM_WAIT() do { \
    __builtin_amdgcn_wave_barrier(); \
    __builtin_amdgcn_s_waitcnt(0xC07F); \
    __builtin_amdgcn_wave_barrier(); \
} while (0)

__device__ __forceinline__ float wave_reduce(float v) {
    v += __shfl_xor(v, 32);
    v += __shfl_xor(v, 16);
    v += __shfl_xor(v, 8);
    v += __shfl_xor(v, 4);
    v += __shfl_xor(v, 2);
    v += __shfl_xor(v, 1);
    return v;
}

__global__ __launch_bounds__(256) void loss_wave(
    const float* __restrict__ reg,   // [B,6,30,2]
    const float* __restrict__ cls,   // [B,6]
    const float* __restrict__ gt,    // [B,30,2]
    const int* __restrict__ has,     // [B,30] bool->int32
    void* __restrict__ ws)
{
    const int tid   = threadIdx.x;
    const int lane  = tid & 63;
    const int wid   = tid >> 6;
    const int gwave = blockIdx.x * 4 + wid;

    // wave-private LDS tiles (no __syncthreads in hot loop)
    __shared__ float4 s_gt[4][RPG * 15];   // {x0,y0,x1,y1} per (row, q)
    __shared__ float4 s_ct[4][RPG * 15];   // {c0,s0,c1,s1} per (row, q)
    __shared__ float  s_red[4][12];

    const int row = lane / 15;             // staging row (valid lane<60)
    const int q   = lane - row * 15;       // timestep pair index

    float acc[12];
    #pragma unroll
    for (int i = 0; i < 12; ++i) acc[i] = 0.f;

    for (int g = gwave; g < NGROUPS; g += NWAVES) {
        const int rb = g * RPG;

        // ---- issue gt/has, then bulk reg: later vmcnt waits for gt/has
        //      leave the 6 reg loads in flight until phase 3 ----
        float4 gv = make_float4(0.f, 0.f, 0.f, 0.f);
        int2   hv = make_int2(0, 0);
        if (lane < 60) {
            gv = ((const float4*)gt)[(size_t)rb * 15 + lane];
            hv = ((const int2*)has)[(size_t)rb * 15 + lane];
        }
        const float4* reg4 = (const float4*)reg + (size_t)rb * 90;
        float4 rv[6];
        #pragma unroll
        for (int i = 0; i < 5; ++i) rv[i] = reg4[lane + 64 * i];
        if (lane < 40) rv[5] = reg4[lane + 320];

        // ---- has bits ----
        unsigned long long bx = __ballot(lane < 60 && hv.x != 0);
        unsigned long long by = __ballot(lane < 60 && hv.y != 0);

        // ---- per-row (lanes 0..3): last idx + issue scattered loads early ----
        unsigned ex = 0u, ey = 0u;
        int last = NPREDS - 1;
        bool valid = false;
        float2 rl[NMODS];
        float2 cc[3];
        if (lane < RPG) {
            ex = (unsigned)((bx >> (15 * lane)) & 0x7FFFull);
            ey = (unsigned)((by >> (15 * lane)) & 0x7FFFull);
            int le = ex ? 2 * (31 - __builtin_clz(ex)) : -1;
            int lo = ey ? 2 * (31 - __builtin_clz(ey)) + 1 : -1;
            last = (le > lo) ? le : lo;
            if (last < 0) last = NPREDS - 1;
            valid = ((ex & ~1u) | ey) != 0u;

            const float2* rr = (const float2*)reg + (size_t)(rb + lane) * 180;
            #pragma unroll
            for (int m = 0; m < NMODS; ++m) rl[m] = rr[m * NPREDS + last];
            const float2* cp = (const float2*)cls + (size_t)(rb + lane) * 3;
            #pragma unroll
            for (int i = 0; i < 3; ++i) cc[i] = cp[i];
        }

        // ---- headings fully in registers, TRIG-FREE ----
        // The (c,s) pair is only used as |c*dx - s*dy|, |s*dx + c*dy|, which is
        // invariant under (c,s) -> (-c,-s). So compute the half-angle DIRECTION
        // via the bisector of the two segment unit vectors; global sign is free.
        //   u+v        = 2*cos((a-b)/2) * (cos m, sin m),  m=(a+b)/2
        //   rot-90(u-v)= 2*sin((a-b)/2) * (cos m, sin m)
        // Pick the larger-norm candidate (always well-conditioned), normalize.
        float e_dx = gv.z - gv.x, e_dy = gv.w - gv.y;            // seg[2q]
        float e_inv = rsqrtf(fmaf(e_dx, e_dx, e_dy * e_dy));
        float uex = e_dx * e_inv, uey = e_dy * e_inv;

        float nx = __shfl(gv.x, lane + 1);
        float ny = __shfl(gv.y, lane + 1);
        float o_dx = nx - gv.z, o_dy = ny - gv.w;                // seg[2q+1]
        float o_inv = rsqrtf(fmaf(o_dx, o_dx, o_dy * o_dy));
        float uox = o_dx * o_inv, uoy = o_dy * o_inv;

        float upx = __shfl(uox, lane - 1);                       // seg[2q-1] unit
        float upy = __shfl(uoy, lane - 1);

        const int base = row * 15;
        float g0x  = __shfl(gv.x, base),      g0y  = __shfl(gv.y, base);
        float g29x = __shfl(gv.z, base + 14), g29y = __shfl(gv.w, base + 14);
        float mdx = g0x - g29x, mdy = g0y - g29y;
        const bool moving = fmaf(mdx, mdx, mdy * mdy) > 4.0f;

        // head[2q]: bisector of (seg[2q], seg[2q-1]); q==0 -> seg[0]
        float sx0 = uex + upx, sy0 = uey + upy;
        float dx0 = uey - upy, dy0 = upx - uex;                  // rot-90(ue-up)
        float na0 = fmaf(sx0, sx0, sy0 * sy0);
        float nb0 = fmaf(dx0, dx0, dy0 * dy0);
        bool ua0 = na0 >= nb0;
        float wx0 = ua0 ? sx0 : dx0, wy0 = ua0 ? sy0 : dy0;
        float wi0 = rsqrtf(ua0 ? na0 : nb0);
        float c0 = wx0 * wi0, s0 = -(wy0 * wi0);                 // theta = -head
        if (q == 0) { c0 = uex; s0 = -uey; }

        // head[2q+1]: bisector of (seg[2q+1], seg[2q]); q==14 -> seg[28]
        float sx1 = uox + uex, sy1 = uoy + uey;
        float dx1 = uoy - uey, dy1 = uex - uox;                  // rot-90(uo-ue)
        float na1 = fmaf(sx1, sx1, sy1 * sy1);
        float nb1 = fmaf(dx1, dx1, dy1 * dy1);
        bool ua1 = na1 >= nb1;
        float wx1 = ua1 ? sx1 : dx1, wy1 = ua1 ? sy1 : dy1;
        float wi1 = rsqrtf(ua1 ? na1 : nb1);
        float c1 = wx1 * wi1, s1 = -(wy1 * wi1);
        if (q == 14) { c1 = uex; s1 = -uey; }

        if (!moving) { c0 = 1.f; s0 = 0.f; c1 = 1.f; s1 = 0.f; }

        if (lane < 60) {
            s_gt[wid][lane] = gv;
            s_ct[wid][lane] = make_float4(c0, s0, c1, s1);
        }
        LGKM_WAIT();   // single LDS turnaround per group

        // ---- per-row scalars (lanes 0..3), loads already in flight ----
        unsigned metaval = 0u;
        if (lane < RPG) {
            float4 gq = s_gt[wid][lane * 15 + (last >> 1)];
            float glx = (last & 1) ? gq.z : gq.x;
            float gly = (last & 1) ? gq.w : gq.y;

            float dists[NMODS];
            #pragma unroll
            for (int m = 0; m < NMODS; ++m) {
                float ax = rl[m].x - glx, ay = rl[m].y - gly;
                dists[m] = sqrtf(ax * ax + ay * ay);
            }
            float mind = dists[0]; int mini = 0;
            #pragma unroll
            for (int m = 1; m < NMODS; ++m)
                if (dists[m] < mind) { mind = dists[m]; mini = m; }

            float cv[NMODS];
            #pragma unroll
            for (int i = 0; i < 3; ++i) { cv[2*i] = cc[i].x; cv[2*i+1] = cc[i].y; }
            float clsmin = cv[0];
            #pragma unroll
            for (int m = 1; m < NMODS; ++m) clsmin = (m == mini) ? cv[m] : clsmin;

            if (valid && (mind < 2.0f)) {
                #pragma unroll
                for (int m = 0; m < NMODS; ++m) {
                    float mgn = clsmin - cv[m];
                    if (((dists[m] - mind) > 0.2f) && (mgn < 0.2f)) {
                        acc[10] += 1.0f;   // numcls
                        acc[9]  += mgn;    // summgn
                    }
                }
            }
            float bc = cv[0]; int top1 = 0;
            #pragma unroll
            for (int m = 1; m < NMODS; ++m)
                if (cv[m] > bc) { bc = cv[m]; top1 = m; }

            if (valid)
                acc[11] += (float)(__builtin_popcount(ex) + __builtin_popcount(ey));

            metaval = (unsigned)mini | ((unsigned)top1 << 4) | (valid ? 256u : 0u);
        }

        // ---- phase 3: de / regloss sweep over register-held reg ----
        #pragma unroll
        for (int i = 0; i < 6; ++i) {
            int k = lane + 64 * i;
            bool act = (i < 5) || (lane < 40);
            int kk = act ? k : 0;
            int rw  = kk / 90;
            int rem = kk - rw * 90;
            int m   = rem / 15;
            int qq  = rem - 15 * m;

            unsigned mv  = (unsigned)__shfl((int)metaval, rw);
            unsigned exr = (unsigned)((bx >> (15 * rw)) & 0x7FFFull);
            unsigned eyr = (unsigned)((by >> (15 * rw)) & 0x7FFFull);
            float4 gp = s_gt[wid][rw * 15 + qq];   // x0 y0 x1 y1
            float4 sp = s_ct[wid][rw * 15 + qq];   // c0 s0 c1 s1
            float4 v  = rv[i];

            unsigned mini = mv & 15u, top1 = (mv >> 4) & 15u;
            bool vld    = (mv & 256u) != 0u;
            bool isTop  = ((unsigned)m == top1);
            bool isBest = ((unsigned)m == mini) && vld;

            if (act) {
                // element 0 (t = 2qq)
                {
                    float dx = fabsf(gp.x - v.x), dy = fabsf(gp.y - v.y);
                    float ax = fabsf(sp.x * dx - sp.y * dy);
                    float ay = fabsf(sp.y * dx + sp.x * dy);
                    acc[0] += ax; acc[1] += ay;
                    if (isTop) { acc[4] += ax; acc[5] += ay; }
                    if (isBest && ((exr >> qq) & 1u)) {
                        float e0 = v.x - gp.x, e1 = v.y - gp.y;
                        float q0 = fabsf(e0), q1 = fabsf(e1);
                        acc[8] += (q0 < 1.f) ? (0.5f * e0 * e0) : (q0 - 0.5f);
                        acc[8] += (q1 < 1.f) ? (0.5f * e1 * e1) : (q1 - 0.5f);
                    }
                }
                // element 1 (t = 2qq+1)
                {
                    float dx = fabsf(gp.z - v.z), dy = fabsf(gp.w - v.w);
                    float ax = fabsf(sp.z * dx - sp.w * dy);
                    float ay = fabsf(sp.w * dx + sp.z * dy);
                    acc[0] += ax; acc[1] += ay;
                    if (isTop) { acc[4] += ax; acc[5] += ay; }
                    if (qq == 14) {                      // t = 29
                        acc[2] += ax; acc[3] += ay;
                        if (isTop) { acc[6] += ax; acc[7] += ay; }
                    }
                    if (isBest && ((eyr >> qq) & 1u)) {
                        float e0 = v.z - gp.z, e1 = v.w - gp.w;
                        float q0 = fabsf(e0), q1 = fabsf(e1);
                        acc[8] += (q0 < 1.f) ? (0.5f * e0 * e0) : (q0 - 0.5f);
                        acc[8] += (q1 < 1.f) ? (0.5f * e1 * e1) : (q1 - 0.5f);
                    }
                }
            }
        }
        __builtin_amdgcn_wave_barrier();  // keep next iter's ds_writes ordered after reads
    }

    // ---- reduce: wave -> block -> strided atomics ----
    #pragma unroll
    for (int i = 0; i < 12; ++i) acc[i] = wave_reduce(acc[i]);

    if (lane == 0) {
        #pragma unroll
        for (int i = 0; i < 12; ++i) s_red[wid][i] = acc[i];
    }
    __syncthreads();
    if (tid < 12) {
        float s = s_red[0][tid] + s_red[1][tid] + s_red[2][tid] + s_red[3][tid];
        atomicAdd(ACC_SLOT(ws, tid), s);
    }
}

__global__ void finalize(void* ws, float* __restrict__ out) {
    if (threadIdx.x == 0) {
        float nc = *ACC_SLOT(ws, 10), nr = *ACC_SLOT(ws, 11);
        float cls_loss = 0.2f * nc - *ACC_SLOT(ws, 9);
        float reg_loss = *ACC_SLOT(ws, 8);
        float loss = cls_loss / (nc + 1e-10f) + reg_loss / (nr + 1e-10f);
        out[0]  = loss;
        out[1]  = cls_loss;
        out[2]  = nc;
        out[3]  = reg_loss;
        out[4]  = nr;
        out[5]  = *ACC_SLOT(ws, 0);
        out[6]  = *ACC_SLOT(ws, 1);
        out[7]  = *ACC_SLOT(ws, 2);
        out[8]  = *ACC_SLOT(ws, 3);
        out[9]  = 23592960.0f;   // 6*B*30
        out[10] = 786432.0f;     // 6*B
        out[11] = *ACC_SLOT(ws, 4);
        out[12] = *ACC_SLOT(ws, 5);
        out[13] = *ACC_SLOT(ws, 6);
        out[14] = *ACC_SLOT(ws, 7);
        out[15] = 3932160.0f;    // B*30
        out[16] = 131072.0f;     // B
    }
}

extern "C" void kernel_launch(void* const* d_in, const int* in_sizes, int n_in,
                              void* d_out, int out_size, void* d_ws, size_t ws_size,
                              hipStream_t stream) {
    const float* reg = (const float*)d_in[0];
    const float* cls = (const float*)d_in[1];
    const float* gt  = (const float*)d_in[2];
    const int*   has = (const int*)d_in[3];
    float* out = (float*)d_out;

    hipMemsetAsync(d_ws, 0, 4096, stream);
    loss_wave<<<NBLK, 256, 0, stream>>>(reg, cls, gt, has, d_ws);
    finalize<<<1, 64, 0, stream>>>(d_ws, out);
}